// Round 8
// baseline (732.515 us; speedup 1.0000x reference)
//
#include <hip/hip_runtime.h>
#include <hip/hip_bf16.h>

#define NNODES 100000
#define NEDGES 1600000
#define FDIM 256
#define SCAN_CHUNK 1024
#define NB_SCAN ((NNODES + SCAN_CHUNK - 1) / SCAN_CHUNK)  // 98

typedef __bf16 bf16x8 __attribute__((ext_vector_type(8)));
typedef __bf16 bf16x4 __attribute__((ext_vector_type(4)));
typedef float f32x4 __attribute__((ext_vector_type(4)));

static __device__ inline __bf16 f2b(float f) { return (__bf16)f; }

// ---------------- CSR build ----------------

__global__ void k_count(const int* __restrict__ dst, int* __restrict__ cnt) {
  int i = blockIdx.x * blockDim.x + threadIdx.x;
  int stride = gridDim.x * blockDim.x;
  for (; i < NEDGES; i += stride) atomicAdd(&cnt[dst[i]], 1);
}

__global__ void k_scan_part(const int* __restrict__ cnt, int* __restrict__ partials) {
  __shared__ int red[256];
  int b = blockIdx.x, t = threadIdx.x;
  int base = b * SCAN_CHUNK + t * 4;
  int s = 0;
#pragma unroll
  for (int j = 0; j < 4; ++j) {
    int idx = base + j;
    if (idx < NNODES) s += cnt[idx];
  }
  red[t] = s;
  __syncthreads();
  for (int o = 128; o > 0; o >>= 1) {
    if (t < o) red[t] += red[t + o];
    __syncthreads();
  }
  if (t == 0) partials[b] = red[0];
}

__global__ void k_scan_partials(int* partials) {
  __shared__ int sc[128];
  int t = threadIdx.x;
  int v = (t < NB_SCAN) ? partials[t] : 0;
  sc[t] = v;
  __syncthreads();
  for (int o = 1; o < 128; o <<= 1) {
    int x = (t >= o) ? sc[t - o] : 0;
    __syncthreads();
    sc[t] += x;
    __syncthreads();
  }
  if (t < NB_SCAN) partials[t] = sc[t] - v;  // exclusive
}

__global__ void k_scan_final(const int* __restrict__ cnt, const int* __restrict__ partials,
                             int* __restrict__ rowptr, int* __restrict__ cursor) {
  __shared__ int sc[256];
  int b = blockIdx.x, t = threadIdx.x;
  int base = b * SCAN_CHUNK + t * 4;
  int c[4];
  int s = 0;
#pragma unroll
  for (int j = 0; j < 4; ++j) {
    int idx = base + j;
    c[j] = (idx < NNODES) ? cnt[idx] : 0;
    s += c[j];
  }
  int v = s;
  sc[t] = s;
  __syncthreads();
  for (int o = 1; o < 256; o <<= 1) {
    int x = (t >= o) ? sc[t - o] : 0;
    __syncthreads();
    sc[t] += x;
    __syncthreads();
  }
  int run = sc[t] - v + partials[b];
#pragma unroll
  for (int j = 0; j < 4; ++j) {
    int idx = base + j;
    if (idx < NNODES) {
      rowptr[idx] = run;
      cursor[idx] = run;
      run += c[j];
      if (idx == NNODES - 1) rowptr[NNODES] = run;
    }
  }
}

// XCD-sliced multi-pass fill (full-line writebacks; see round-6 note).
__global__ void k_fill(const int* __restrict__ src, const int* __restrict__ dst,
                       int* cursor, int* __restrict__ col) {
  const int xcd = blockIdx.x & 7;
  const int tid = (blockIdx.x >> 3) * 256 + threadIdx.x;  // 0..65535
  const int stride = 256 * 256;
#pragma unroll 1
  for (int sp = 0; sp < 4; ++sp) {
    const int lo = xcd * 12500 + sp * 3125;
    const int hi = lo + 3125;
    for (int i = tid; i < NEDGES; i += stride) {
      int d = dst[i];
      if (d >= lo && d < hi) {
        int p = atomicAdd(&cursor[d], 1);
        col[p] = src[i];
      }
    }
  }
}

// ---------------- weight prep: f32 [K][N] -> bf16 [N][K] (transposed) ----------------

__global__ void k_prep_w(const float* __restrict__ w1a, const float* __restrict__ w1b,
                         const float* __restrict__ w2a, const float* __restrict__ w2b,
                         __bf16* __restrict__ wt) {
  int mat = blockIdx.x >> 8;
  int n = blockIdx.x & 255;
  const float* W = (mat == 0) ? w1a : (mat == 1) ? w1b : (mat == 2) ? w2a : w2b;
  __bf16* dst = wt + (size_t)mat * 65536 + n * 256;
  int k = threadIdx.x;
  dst[k] = f2b(W[k * 256 + n]);
}

// embeddings f32 -> bf16 (same layout, [field][1000][64])
__global__ void k_prep_emb(const float* __restrict__ e0, const float* __restrict__ e1,
                           const float* __restrict__ e2, const float* __restrict__ e3,
                           __bf16* __restrict__ embt) {
  int c = blockIdx.x;           // 0..999
  int f = threadIdx.x >> 6;     // 0..3
  int e = threadIdx.x & 63;     // 0..63
  const float* E = (f == 0) ? e0 : (f == 1) ? e1 : (f == 2) ? e2 : e3;
  embt[(size_t)f * 64000 + c * 64 + e] = f2b(E[c * 64 + e]);
}

// ---------------- conv1 aggregation fused with embedding lookup ----------------
// One wave per node, 8 groups x 8 lanes; group g handles edges s+g, s+g+8, ...
// (8 independent chains/wave). Lane (g,q) covers cols q*32..q*32+31 (64 B),
// field f=q>>1. No cross-lane ops in divergent code.

__global__ __launch_bounds__(256) void k_agg_embed(
    const int* __restrict__ xcat, const __bf16* __restrict__ embt,
    const int* __restrict__ rowptr, const int* __restrict__ col,
    __bf16* __restrict__ out) {
  int wid = (blockIdx.x * 256 + threadIdx.x) >> 6;
  int lane = threadIdx.x & 63;
  if (wid >= NNODES) return;
  const int g = lane >> 3, q = lane & 7;
  const int f = q >> 1;
  const __bf16* tab = embt + (size_t)f * 64000 + (q & 1) * 32;

  float acc[32];
  if (g == 0) {
    int cf = xcat[wid * 4 + f];
    const bf16x8* r = (const bf16x8*)(tab + cf * 64);
    bf16x8 v0 = r[0], v1 = r[1], v2 = r[2], v3 = r[3];
#pragma unroll
    for (int t = 0; t < 8; ++t) {
      acc[t] = (float)v0[t]; acc[8 + t] = (float)v1[t];
      acc[16 + t] = (float)v2[t]; acc[24 + t] = (float)v3[t];
    }
  } else {
#pragma unroll
    for (int t = 0; t < 32; ++t) acc[t] = 0.f;
  }

  int s = rowptr[wid], e = rowptr[wid + 1];
#pragma unroll 2
  for (int p = s + g; p < e; p += 8) {
    int jj = col[p];
    int cc = xcat[jj * 4 + f];
    const bf16x8* r = (const bf16x8*)(tab + cc * 64);
    bf16x8 v0 = r[0], v1 = r[1], v2 = r[2], v3 = r[3];
#pragma unroll
    for (int t = 0; t < 8; ++t) {
      acc[t] += (float)v0[t]; acc[8 + t] += (float)v1[t];
      acc[16 + t] += (float)v2[t]; acc[24 + t] += (float)v3[t];
    }
  }
  // cross-group reduce (all 64 lanes active here)
#pragma unroll
  for (int t = 0; t < 32; ++t) {
    acc[t] += __shfl_xor(acc[t], 8);
    acc[t] += __shfl_xor(acc[t], 16);
    acc[t] += __shfl_xor(acc[t], 32);
  }
  // lane (g,q) writes cols q*32 + g*4 .. +3 (static select)
  float r0, r1, r2, r3;
  switch (g) {
    case 0: r0 = acc[0];  r1 = acc[1];  r2 = acc[2];  r3 = acc[3];  break;
    case 1: r0 = acc[4];  r1 = acc[5];  r2 = acc[6];  r3 = acc[7];  break;
    case 2: r0 = acc[8];  r1 = acc[9];  r2 = acc[10]; r3 = acc[11]; break;
    case 3: r0 = acc[12]; r1 = acc[13]; r2 = acc[14]; r3 = acc[15]; break;
    case 4: r0 = acc[16]; r1 = acc[17]; r2 = acc[18]; r3 = acc[19]; break;
    case 5: r0 = acc[20]; r1 = acc[21]; r2 = acc[22]; r3 = acc[23]; break;
    case 6: r0 = acc[24]; r1 = acc[25]; r2 = acc[26]; r3 = acc[27]; break;
    default: r0 = acc[28]; r1 = acc[29]; r2 = acc[30]; r3 = acc[31]; break;
  }
  bf16x4 o;
  o[0] = f2b(r0); o[1] = f2b(r1); o[2] = f2b(r2); o[3] = f2b(r3);
  *((bf16x4*)(out + (size_t)wid * FDIM + q * 32 + g * 4)) = o;
}

// ---------------- generic aggregation (conv2, bf16 rows, 8-way edge ILP) ----------------

__global__ __launch_bounds__(256) void k_agg(const __bf16* __restrict__ xin,
                                             const int* __restrict__ rowptr,
                                             const int* __restrict__ col,
                                             __bf16* __restrict__ out) {
  int wid = (blockIdx.x * 256 + threadIdx.x) >> 6;
  int lane = threadIdx.x & 63;
  if (wid >= NNODES) return;
  const int g = lane >> 3, q = lane & 7;

  float acc[32];
  if (g == 0) {
    const bf16x8* r = (const bf16x8*)(xin + (size_t)wid * FDIM + q * 32);
    bf16x8 v0 = r[0], v1 = r[1], v2 = r[2], v3 = r[3];
#pragma unroll
    for (int t = 0; t < 8; ++t) {
      acc[t] = (float)v0[t]; acc[8 + t] = (float)v1[t];
      acc[16 + t] = (float)v2[t]; acc[24 + t] = (float)v3[t];
    }
  } else {
#pragma unroll
    for (int t = 0; t < 32; ++t) acc[t] = 0.f;
  }

  int s = rowptr[wid], e = rowptr[wid + 1];
#pragma unroll 2
  for (int p = s + g; p < e; p += 8) {
    int jj = col[p];
    const bf16x8* r = (const bf16x8*)(xin + (size_t)jj * FDIM + q * 32);
    bf16x8 v0 = r[0], v1 = r[1], v2 = r[2], v3 = r[3];
#pragma unroll
    for (int t = 0; t < 8; ++t) {
      acc[t] += (float)v0[t]; acc[8 + t] += (float)v1[t];
      acc[16 + t] += (float)v2[t]; acc[24 + t] += (float)v3[t];
    }
  }
#pragma unroll
  for (int t = 0; t < 32; ++t) {
    acc[t] += __shfl_xor(acc[t], 8);
    acc[t] += __shfl_xor(acc[t], 16);
    acc[t] += __shfl_xor(acc[t], 32);
  }
  float r0, r1, r2, r3;
  switch (g) {
    case 0: r0 = acc[0];  r1 = acc[1];  r2 = acc[2];  r3 = acc[3];  break;
    case 1: r0 = acc[4];  r1 = acc[5];  r2 = acc[6];  r3 = acc[7];  break;
    case 2: r0 = acc[8];  r1 = acc[9];  r2 = acc[10]; r3 = acc[11]; break;
    case 3: r0 = acc[12]; r1 = acc[13]; r2 = acc[14]; r3 = acc[15]; break;
    case 4: r0 = acc[16]; r1 = acc[17]; r2 = acc[18]; r3 = acc[19]; break;
    case 5: r0 = acc[20]; r1 = acc[21]; r2 = acc[22]; r3 = acc[23]; break;
    case 6: r0 = acc[24]; r1 = acc[25]; r2 = acc[26]; r3 = acc[27]; break;
    default: r0 = acc[28]; r1 = acc[29]; r2 = acc[30]; r3 = acc[31]; break;
  }
  bf16x4 o;
  o[0] = f2b(r0); o[1] = f2b(r1); o[2] = f2b(r2); o[3] = f2b(r3);
  *((bf16x4*)(out + (size_t)wid * FDIM + q * 32 + g * 4)) = o;
}

// ---------------- MFMA MLP: relu(in@Wa+ba)@Wb+bb [-> relu] -> LN ----------------
// BM=64 rows per block, 256 threads = 4 waves (wave w -> cols w*64..w*64+63).
// sA: [64][264] bf16 in LDS. B-fragments loaded DIRECTLY from global Wt
// (128 KB, L2-resident) -> no sW staging, 3 barriers/block instead of 34.

#define BM 64
#define NBLK_MLP ((NNODES + BM - 1) / BM)  // 1563
#define LDA 264

__device__ inline void gemm_direct(const __bf16* __restrict__ WtG, const __bf16* sA,
                                   f32x4 acc[4][4], int lane, int wid) {
  const int ko = (lane >> 4) * 8;
  const int ar = lane & 15;
  const __bf16* Wp = WtG + (size_t)(wid * 64 + ar) * 256 + ko;
#pragma unroll
  for (int ks = 0; ks < 8; ++ks) {
    bf16x8 a0 = *(const bf16x8*)&sA[(ar +  0) * LDA + ks * 32 + ko];
    bf16x8 a1 = *(const bf16x8*)&sA[(ar + 16) * LDA + ks * 32 + ko];
    bf16x8 a2 = *(const bf16x8*)&sA[(ar + 32) * LDA + ks * 32 + ko];
    bf16x8 a3 = *(const bf16x8*)&sA[(ar + 48) * LDA + ks * 32 + ko];
#pragma unroll
    for (int n = 0; n < 4; ++n) {
      bf16x8 b = *(const bf16x8*)&Wp[n * 16 * 256 + ks * 32];
      acc[0][n] = __builtin_amdgcn_mfma_f32_16x16x32_bf16(a0, b, acc[0][n], 0, 0, 0);
      acc[1][n] = __builtin_amdgcn_mfma_f32_16x16x32_bf16(a1, b, acc[1][n], 0, 0, 0);
      acc[2][n] = __builtin_amdgcn_mfma_f32_16x16x32_bf16(a2, b, acc[2][n], 0, 0, 0);
      acc[3][n] = __builtin_amdgcn_mfma_f32_16x16x32_bf16(a3, b, acc[3][n], 0, 0, 0);
    }
  }
}

template <int RELU_BEFORE_LN, int OUT_BF16>
__global__ __launch_bounds__(256, 4) void k_mlp_mfma(
    const __bf16* __restrict__ in, void* __restrict__ outp,
    const __bf16* __restrict__ WtA, const float* __restrict__ ba,
    const __bf16* __restrict__ WtB, const float* __restrict__ bb,
    const float* __restrict__ gam, const float* __restrict__ bet) {
  __shared__ __bf16 sA[BM * LDA];
  __shared__ float sSum[BM], sSqs[BM];

  const int tid = threadIdx.x;
  const int lane = tid & 63;
  const int wid = tid >> 6;
  const size_t rowbase = (size_t)blockIdx.x * BM;

  if (tid < BM) { sSum[tid] = 0.f; sSqs[tid] = 0.f; }

  // ---- stage input tile (bf16); tail rows read in-ws garbage, never stored ----
  {
    int r = tid >> 2;
    int cb = (tid & 3) * 64;
    const bf16x8* g = (const bf16x8*)(in + (rowbase + (size_t)r) * FDIM + cb);
    bf16x8* s = (bf16x8*)&sA[r * LDA + cb];
#pragma unroll
    for (int i = 0; i < 8; ++i) s[i] = g[i];
  }
  __syncthreads();

  f32x4 acc[4][4];
#pragma unroll
  for (int m = 0; m < 4; ++m)
#pragma unroll
    for (int n = 0; n < 4; ++n) acc[m][n] = (f32x4)0.f;

  // ---- GEMM1 ----
  gemm_direct(WtA, sA, acc, lane, wid);
  __syncthreads();  // all waves done reading sA

  // epilogue 1: bias + relu -> H (bf16) overwrites sA
  {
    float bias[4];
#pragma unroll
    for (int n = 0; n < 4; ++n) bias[n] = ba[wid * 64 + n * 16 + (lane & 15)];
#pragma unroll
    for (int m = 0; m < 4; ++m)
#pragma unroll
      for (int n = 0; n < 4; ++n) {
        int c = wid * 64 + n * 16 + (lane & 15);
#pragma unroll
        for (int j = 0; j < 4; ++j) {
          int r = m * 16 + (lane >> 4) * 4 + j;
          float v = acc[m][n][j] + bias[n];
          v = fmaxf(v, 0.f);
          sA[r * LDA + c] = f2b(v);
        }
      }
  }
  __syncthreads();  // H visible to all waves
#pragma unroll
  for (int m = 0; m < 4; ++m)
#pragma unroll
    for (int n = 0; n < 4; ++n) acc[m][n] = (f32x4)0.f;

  // ---- GEMM2 ----
  gemm_direct(WtB, sA, acc, lane, wid);

  // epilogue 2: bias (+relu) + LayerNorm -> global (guarded rows)
  {
    float bias2[4], gm[4], bt[4];
#pragma unroll
    for (int n = 0; n < 4; ++n) {
      int c = wid * 64 + n * 16 + (lane & 15);
      bias2[n] = bb[c];
      gm[n] = gam[c];
      bt[n] = bet[c];
    }
#pragma unroll
    for (int m = 0; m < 4; ++m)
#pragma unroll
      for (int n = 0; n < 4; ++n)
#pragma unroll
        for (int j = 0; j < 4; ++j) {
          float v = acc[m][n][j] + bias2[n];
          if (RELU_BEFORE_LN) v = fmaxf(v, 0.f);
          acc[m][n][j] = v;
        }
    // row sums (each wave covers 64 of 256 cols; cross-wave via LDS atomics)
#pragma unroll
    for (int m = 0; m < 4; ++m)
#pragma unroll
      for (int j = 0; j < 4; ++j) {
        float s1 = acc[m][0][j] + acc[m][1][j] + acc[m][2][j] + acc[m][3][j];
        float s2 = acc[m][0][j] * acc[m][0][j] + acc[m][1][j] * acc[m][1][j] +
                   acc[m][2][j] * acc[m][2][j] + acc[m][3][j] * acc[m][3][j];
#pragma unroll
        for (int o = 1; o < 16; o <<= 1) {
          s1 += __shfl_xor(s1, o);
          s2 += __shfl_xor(s2, o);
        }
        if ((lane & 15) == 0) {
          int r = m * 16 + (lane >> 4) * 4 + j;
          atomicAdd(&sSum[r], s1);
          atomicAdd(&sSqs[r], s2);
        }
      }
    __syncthreads();
#pragma unroll
    for (int m = 0; m < 4; ++m)
#pragma unroll
      for (int j = 0; j < 4; ++j) {
        int r = m * 16 + (lane >> 4) * 4 + j;
        if (rowbase + r >= NNODES) continue;
        float mean = sSum[r] * (1.f / 256.f);
        float var = sSqs[r] * (1.f / 256.f) - mean * mean;
        float rstd = rsqrtf(var + 1e-5f);
#pragma unroll
        for (int n = 0; n < 4; ++n) {
          int c = wid * 64 + n * 16 + (lane & 15);
          float v = (acc[m][n][j] - mean) * rstd * gm[n] + bt[n];
          if (OUT_BF16)
            ((__bf16*)outp)[(rowbase + r) * FDIM + c] = f2b(v);
          else
            ((float*)outp)[(rowbase + r) * FDIM + c] = v;
        }
      }
  }
}

// ---------------- launch ----------------

extern "C" void kernel_launch(void* const* d_in, const int* in_sizes, int n_in,
                              void* d_out, int out_size, void* d_ws, size_t ws_size,
                              hipStream_t stream) {
  const int* xcat = (const int*)d_in[0];
  const int* edge = (const int*)d_in[1];
  const float* emb0 = (const float*)d_in[2];
  const float* emb1 = (const float*)d_in[3];
  const float* emb2 = (const float*)d_in[4];
  const float* emb3 = (const float*)d_in[5];
  const float* w1a = (const float*)d_in[6];
  const float* b1a = (const float*)d_in[7];
  const float* w1b = (const float*)d_in[8];
  const float* b1b = (const float*)d_in[9];
  const float* w2a = (const float*)d_in[10];
  const float* b2a = (const float*)d_in[11];
  const float* w2b = (const float*)d_in[12];
  const float* b2b = (const float*)d_in[13];
  const float* ln1g = (const float*)d_in[14];
  const float* ln1b = (const float*)d_in[15];
  const float* ln2g = (const float*)d_in[16];
  const float* ln2b = (const float*)d_in[17];
  float* outF = (float*)d_out;

  const int* srcP = edge;           // edge_index[0]
  const int* dstP = edge + NEDGES;  // edge_index[1]

  // workspace layout: bufA(bf16) | bufB(bf16) | col | rowptr | U
  // U = {cnt,cursor,partials} during CSR build, then overlaid by {wt, embt}.
  __bf16* bufA = (__bf16*)d_ws;                         // N*256 bf16 (agg out)
  __bf16* bufB = bufA + (size_t)NNODES * FDIM;          // N*256 bf16 (h1)
  int* col = (int*)(bufB + (size_t)NNODES * FDIM);      // E
  int* rowptr = col + NEDGES;                           // N+1 (padded to N+4)
  char* U = (char*)(rowptr + NNODES + 4);
  int* cnt = (int*)U;                                   // N
  int* cursor = cnt + NNODES;                           // N
  int* partials = cursor + NNODES;                      // 128
  __bf16* wt = (__bf16*)U;                              // 4 * 256 * 256 bf16
  __bf16* embt = wt + 262144;                           // 4 * 1000 * 64 bf16

  // ---- CSR build ----
  hipMemsetAsync(cnt, 0, (size_t)NNODES * sizeof(int), stream);
  k_count<<<2048, 256, 0, stream>>>(dstP, cnt);
  k_scan_part<<<NB_SCAN, 256, 0, stream>>>(cnt, partials);
  k_scan_partials<<<1, 128, 0, stream>>>(partials);
  k_scan_final<<<NB_SCAN, 256, 0, stream>>>(cnt, partials, rowptr, cursor);
  k_fill<<<2048, 256, 0, stream>>>(srcP, dstP, cursor, col);

  // ---- weight + embedding prep (cnt/cursor/partials dead now) ----
  k_prep_w<<<1024, 256, 0, stream>>>(w1a, w1b, w2a, w2b, wt);
  k_prep_emb<<<1000, 256, 0, stream>>>(emb0, emb1, emb2, emb3, embt);

  // ---- conv1: fused embed + aggregate -> bufA (bf16) ----
  k_agg_embed<<<NNODES / 4, 256, 0, stream>>>(xcat, embt, rowptr, col, bufA);
  // ---- conv1 MLP + relu + LN -> bufB (bf16 h1) ----
  k_mlp_mfma<1, 1><<<NBLK_MLP, 256, 0, stream>>>(bufA, bufB, wt, b1a, wt + 65536, b1b, ln1g, ln1b);
  // ---- conv2: aggregate h1 -> bufA (bf16) ----
  k_agg<<<NNODES / 4, 256, 0, stream>>>(bufB, rowptr, col, bufA);
  // ---- conv2 MLP + LN -> d_out (f32) ----
  k_mlp_mfma<0, 0><<<NBLK_MLP, 256, 0, stream>>>(bufA, outF, wt + 131072, b2a, wt + 196608, b2b, ln2g, ln2b);
}

// Round 9
// 624.834 us; speedup vs baseline: 1.1723x; 1.1723x over previous
//
#include <hip/hip_runtime.h>
#include <hip/hip_bf16.h>

#define NNODES 100000
#define NEDGES 1600000
#define FDIM 256
#define SCAN_CHUNK 1024
#define NB_SCAN ((NNODES + SCAN_CHUNK - 1) / SCAN_CHUNK)  // 98

typedef __bf16 bf16x8 __attribute__((ext_vector_type(8)));
typedef __bf16 bf16x4 __attribute__((ext_vector_type(4)));
typedef float f32x4 __attribute__((ext_vector_type(4)));

static __device__ inline __bf16 f2b(float f) { return (__bf16)f; }

// ---------------- CSR build ----------------

__global__ void k_count(const int* __restrict__ dst, int* __restrict__ cnt) {
  int i = blockIdx.x * blockDim.x + threadIdx.x;
  int stride = gridDim.x * blockDim.x;
  for (; i < NEDGES; i += stride) atomicAdd(&cnt[dst[i]], 1);
}

__global__ void k_scan_part(const int* __restrict__ cnt, int* __restrict__ partials) {
  __shared__ int red[256];
  int b = blockIdx.x, t = threadIdx.x;
  int base = b * SCAN_CHUNK + t * 4;
  int s = 0;
#pragma unroll
  for (int j = 0; j < 4; ++j) {
    int idx = base + j;
    if (idx < NNODES) s += cnt[idx];
  }
  red[t] = s;
  __syncthreads();
  for (int o = 128; o > 0; o >>= 1) {
    if (t < o) red[t] += red[t + o];
    __syncthreads();
  }
  if (t == 0) partials[b] = red[0];
}

__global__ void k_scan_partials(int* partials) {
  __shared__ int sc[128];
  int t = threadIdx.x;
  int v = (t < NB_SCAN) ? partials[t] : 0;
  sc[t] = v;
  __syncthreads();
  for (int o = 1; o < 128; o <<= 1) {
    int x = (t >= o) ? sc[t - o] : 0;
    __syncthreads();
    sc[t] += x;
    __syncthreads();
  }
  if (t < NB_SCAN) partials[t] = sc[t] - v;  // exclusive
}

__global__ void k_scan_final(const int* __restrict__ cnt, const int* __restrict__ partials,
                             int* __restrict__ rowptr, int* __restrict__ cursor) {
  __shared__ int sc[256];
  int b = blockIdx.x, t = threadIdx.x;
  int base = b * SCAN_CHUNK + t * 4;
  int c[4];
  int s = 0;
#pragma unroll
  for (int j = 0; j < 4; ++j) {
    int idx = base + j;
    c[j] = (idx < NNODES) ? cnt[idx] : 0;
    s += c[j];
  }
  int v = s;
  sc[t] = s;
  __syncthreads();
  for (int o = 1; o < 256; o <<= 1) {
    int x = (t >= o) ? sc[t - o] : 0;
    __syncthreads();
    sc[t] += x;
    __syncthreads();
  }
  int run = sc[t] - v + partials[b];
#pragma unroll
  for (int j = 0; j < 4; ++j) {
    int idx = base + j;
    if (idx < NNODES) {
      rowptr[idx] = run;
      cursor[idx] = run;
      run += c[j];
      if (idx == NNODES - 1) rowptr[NNODES] = run;
    }
  }
}

// XCD-sliced fill, single pass: XCD b owns dst nodes [b*12500, (b+1)*12500);
// active cursor window ~800 KB stays L2-resident -> full-line writebacks.
__global__ void k_fill(const int* __restrict__ src, const int* __restrict__ dst,
                       int* cursor, int* __restrict__ col) {
  const int xcd = blockIdx.x & 7;
  const int tid = (blockIdx.x >> 3) * 256 + threadIdx.x;  // 0..65535
  const int stride = 256 * 256;
  const int lo = xcd * 12500, hi = lo + 12500;
  for (int i = tid; i < NEDGES; i += stride) {
    int d = dst[i];
    if (d >= lo && d < hi) {
      int p = atomicAdd(&cursor[d], 1);
      col[p] = src[i];
    }
  }
}

// ---------------- weight prep: f32 [K][N] -> bf16 [N][K] (transposed) ----------------

__global__ void k_prep_w(const float* __restrict__ w1a, const float* __restrict__ w1b,
                         const float* __restrict__ w2a, const float* __restrict__ w2b,
                         __bf16* __restrict__ wt) {
  int mat = blockIdx.x >> 8;
  int n = blockIdx.x & 255;
  const float* W = (mat == 0) ? w1a : (mat == 1) ? w1b : (mat == 2) ? w2a : w2b;
  __bf16* dst = wt + (size_t)mat * 65536 + n * 256;
  int k = threadIdx.x;
  dst[k] = f2b(W[k * 256 + n]);
}

// embeddings f32 -> bf16 (same layout, [field][1000][64])
__global__ void k_prep_emb(const float* __restrict__ e0, const float* __restrict__ e1,
                           const float* __restrict__ e2, const float* __restrict__ e3,
                           __bf16* __restrict__ embt) {
  int c = blockIdx.x;           // 0..999
  int f = threadIdx.x >> 6;     // 0..3
  int e = threadIdx.x & 63;     // 0..63
  const float* E = (f == 0) ? e0 : (f == 1) ? e1 : (f == 2) ? e2 : e3;
  embt[(size_t)f * 64000 + c * 64 + e] = f2b(E[c * 64 + e]);
}

// ---------------- conv1 aggregation fused with embedding lookup ----------------
// One wave per node, 4 groups x 16 lanes; group g handles edges s+g, s+g+4, ...
// Software pipeline: col[p+4] and xcat for the NEXT edge are issued while the
// current table row is loading (3-deep chain col->xcat->emb becomes max, not sum).

__global__ __launch_bounds__(256) void k_agg_embed(
    const int* __restrict__ xcat, const __bf16* __restrict__ embt,
    const int* __restrict__ rowptr, const int* __restrict__ col,
    __bf16* __restrict__ out) {
  int wid = (blockIdx.x * 256 + threadIdx.x) >> 6;
  int lane = threadIdx.x & 63;
  if (wid >= NNODES) return;
  const int g = lane >> 4, q = lane & 15;
  const int f = q >> 2;
  const __bf16* tab = embt + (size_t)f * 64000 + (q & 3) * 16;

  float acc[16];
  if (g == 0) {
    int cf = xcat[wid * 4 + f];
    const bf16x8* r = (const bf16x8*)(tab + cf * 64);
    bf16x8 v0 = r[0], v1 = r[1];
#pragma unroll
    for (int t = 0; t < 8; ++t) { acc[t] = (float)v0[t]; acc[8 + t] = (float)v1[t]; }
  } else {
#pragma unroll
    for (int t = 0; t < 16; ++t) acc[t] = 0.f;
  }

  int s = rowptr[wid], e = rowptr[wid + 1];
  int p = s + g;
  int jj = (p < e) ? col[p] : 0;
  int cc = xcat[jj * 4 + f];
#pragma unroll 2
  for (; p < e; p += 4) {
    int pn = p + 4;
    int jn = (pn < e) ? col[pn] : 0;
    int cn = xcat[jn * 4 + f];
    const bf16x8* r = (const bf16x8*)(tab + cc * 64);
    bf16x8 v0 = r[0], v1 = r[1];
#pragma unroll
    for (int t = 0; t < 8; ++t) { acc[t] += (float)v0[t]; acc[8 + t] += (float)v1[t]; }
    jj = jn; cc = cn;
  }
  // cross-group reduce (all 64 lanes active here)
#pragma unroll
  for (int t = 0; t < 16; ++t) {
    acc[t] += __shfl_xor(acc[t], 16);
    acc[t] += __shfl_xor(acc[t], 32);
  }
  float r0, r1, r2, r3;
  if (g == 0)      { r0 = acc[0];  r1 = acc[1];  r2 = acc[2];  r3 = acc[3];  }
  else if (g == 1) { r0 = acc[4];  r1 = acc[5];  r2 = acc[6];  r3 = acc[7];  }
  else if (g == 2) { r0 = acc[8];  r1 = acc[9];  r2 = acc[10]; r3 = acc[11]; }
  else             { r0 = acc[12]; r1 = acc[13]; r2 = acc[14]; r3 = acc[15]; }
  bf16x4 o;
  o[0] = f2b(r0); o[1] = f2b(r1); o[2] = f2b(r2); o[3] = f2b(r3);
  *((bf16x4*)(out + (size_t)wid * FDIM + q * 16 + g * 4)) = o;
}

// ---------------- generic aggregation (conv2, 4-way edge ILP + index prefetch) ----------------

__global__ __launch_bounds__(256) void k_agg(const __bf16* __restrict__ xin,
                                             const int* __restrict__ rowptr,
                                             const int* __restrict__ col,
                                             __bf16* __restrict__ out) {
  int wid = (blockIdx.x * 256 + threadIdx.x) >> 6;
  int lane = threadIdx.x & 63;
  if (wid >= NNODES) return;
  const int g = lane >> 4, q = lane & 15;

  float acc[16];
  if (g == 0) {
    const bf16x8* r = (const bf16x8*)(xin + (size_t)wid * FDIM + q * 16);
    bf16x8 v0 = r[0], v1 = r[1];
#pragma unroll
    for (int t = 0; t < 8; ++t) { acc[t] = (float)v0[t]; acc[8 + t] = (float)v1[t]; }
  } else {
#pragma unroll
    for (int t = 0; t < 16; ++t) acc[t] = 0.f;
  }

  int s = rowptr[wid], e = rowptr[wid + 1];
  int p = s + g;
  int jj = (p < e) ? col[p] : 0;
#pragma unroll 2
  for (; p < e; p += 4) {
    int pn = p + 4;
    int jn = (pn < e) ? col[pn] : 0;
    const bf16x8* r = (const bf16x8*)(xin + (size_t)jj * FDIM + q * 16);
    bf16x8 v0 = r[0], v1 = r[1];
#pragma unroll
    for (int t = 0; t < 8; ++t) { acc[t] += (float)v0[t]; acc[8 + t] += (float)v1[t]; }
    jj = jn;
  }
#pragma unroll
  for (int t = 0; t < 16; ++t) {
    acc[t] += __shfl_xor(acc[t], 16);
    acc[t] += __shfl_xor(acc[t], 32);
  }
  float r0, r1, r2, r3;
  if (g == 0)      { r0 = acc[0];  r1 = acc[1];  r2 = acc[2];  r3 = acc[3];  }
  else if (g == 1) { r0 = acc[4];  r1 = acc[5];  r2 = acc[6];  r3 = acc[7];  }
  else if (g == 2) { r0 = acc[8];  r1 = acc[9];  r2 = acc[10]; r3 = acc[11]; }
  else             { r0 = acc[12]; r1 = acc[13]; r2 = acc[14]; r3 = acc[15]; }
  bf16x4 o;
  o[0] = f2b(r0); o[1] = f2b(r1); o[2] = f2b(r2); o[3] = f2b(r3);
  *((bf16x4*)(out + (size_t)wid * FDIM + q * 16 + g * 4)) = o;
}

// ---------------- MFMA MLP: relu(in@Wa+ba)@Wb+bb [-> relu] -> LN ----------------
// BM=64 rows per block, 256 threads = 4 waves (wave w -> cols w*64..w*64+63).
// sA: [64][264] bf16 in LDS. B-fragments loaded DIRECTLY from global Wt
// (128 KB, L2-resident) -> no sW staging, 3 barriers/block.

#define BM 64
#define NBLK_MLP ((NNODES + BM - 1) / BM)  // 1563
#define LDA 264

__device__ inline void gemm_direct(const __bf16* __restrict__ WtG, const __bf16* sA,
                                   f32x4 acc[4][4], int lane, int wid) {
  const int ko = (lane >> 4) * 8;
  const int ar = lane & 15;
  const __bf16* Wp = WtG + (size_t)(wid * 64 + ar) * 256 + ko;
#pragma unroll
  for (int ks = 0; ks < 8; ++ks) {
    bf16x8 a0 = *(const bf16x8*)&sA[(ar +  0) * LDA + ks * 32 + ko];
    bf16x8 a1 = *(const bf16x8*)&sA[(ar + 16) * LDA + ks * 32 + ko];
    bf16x8 a2 = *(const bf16x8*)&sA[(ar + 32) * LDA + ks * 32 + ko];
    bf16x8 a3 = *(const bf16x8*)&sA[(ar + 48) * LDA + ks * 32 + ko];
#pragma unroll
    for (int n = 0; n < 4; ++n) {
      bf16x8 b = *(const bf16x8*)&Wp[n * 16 * 256 + ks * 32];
      acc[0][n] = __builtin_amdgcn_mfma_f32_16x16x32_bf16(a0, b, acc[0][n], 0, 0, 0);
      acc[1][n] = __builtin_amdgcn_mfma_f32_16x16x32_bf16(a1, b, acc[1][n], 0, 0, 0);
      acc[2][n] = __builtin_amdgcn_mfma_f32_16x16x32_bf16(a2, b, acc[2][n], 0, 0, 0);
      acc[3][n] = __builtin_amdgcn_mfma_f32_16x16x32_bf16(a3, b, acc[3][n], 0, 0, 0);
    }
  }
}

template <int RELU_BEFORE_LN, int OUT_BF16>
__global__ __launch_bounds__(256, 4) void k_mlp_mfma(
    const __bf16* __restrict__ in, void* __restrict__ outp,
    const __bf16* __restrict__ WtA, const float* __restrict__ ba,
    const __bf16* __restrict__ WtB, const float* __restrict__ bb,
    const float* __restrict__ gam, const float* __restrict__ bet) {
  __shared__ __bf16 sA[BM * LDA];
  __shared__ float sSum[BM], sSqs[BM];

  const int tid = threadIdx.x;
  const int lane = tid & 63;
  const int wid = tid >> 6;
  const size_t rowbase = (size_t)blockIdx.x * BM;

  if (tid < BM) { sSum[tid] = 0.f; sSqs[tid] = 0.f; }

  // ---- stage input tile (bf16); tail rows read in-ws garbage, never stored ----
  {
    int r = tid >> 2;
    int cb = (tid & 3) * 64;
    const bf16x8* g = (const bf16x8*)(in + (rowbase + (size_t)r) * FDIM + cb);
    bf16x8* s = (bf16x8*)&sA[r * LDA + cb];
#pragma unroll
    for (int i = 0; i < 8; ++i) s[i] = g[i];
  }
  __syncthreads();

  f32x4 acc[4][4];
#pragma unroll
  for (int m = 0; m < 4; ++m)
#pragma unroll
    for (int n = 0; n < 4; ++n) acc[m][n] = (f32x4)0.f;

  // ---- GEMM1 ----
  gemm_direct(WtA, sA, acc, lane, wid);
  __syncthreads();  // all waves done reading sA

  // epilogue 1: bias + relu -> H (bf16) overwrites sA
  {
    float bias[4];
#pragma unroll
    for (int n = 0; n < 4; ++n) bias[n] = ba[wid * 64 + n * 16 + (lane & 15)];
#pragma unroll
    for (int m = 0; m < 4; ++m)
#pragma unroll
      for (int n = 0; n < 4; ++n) {
        int c = wid * 64 + n * 16 + (lane & 15);
#pragma unroll
        for (int j = 0; j < 4; ++j) {
          int r = m * 16 + (lane >> 4) * 4 + j;
          float v = acc[m][n][j] + bias[n];
          v = fmaxf(v, 0.f);
          sA[r * LDA + c] = f2b(v);
        }
      }
  }
  __syncthreads();  // H visible to all waves
#pragma unroll
  for (int m = 0; m < 4; ++m)
#pragma unroll
    for (int n = 0; n < 4; ++n) acc[m][n] = (f32x4)0.f;

  // ---- GEMM2 ----
  gemm_direct(WtB, sA, acc, lane, wid);

  // epilogue 2: bias (+relu) + LayerNorm -> global (guarded rows)
  {
    float bias2[4], gm[4], bt[4];
#pragma unroll
    for (int n = 0; n < 4; ++n) {
      int c = wid * 64 + n * 16 + (lane & 15);
      bias2[n] = bb[c];
      gm[n] = gam[c];
      bt[n] = bet[c];
    }
#pragma unroll
    for (int m = 0; m < 4; ++m)
#pragma unroll
      for (int n = 0; n < 4; ++n)
#pragma unroll
        for (int j = 0; j < 4; ++j) {
          float v = acc[m][n][j] + bias2[n];
          if (RELU_BEFORE_LN) v = fmaxf(v, 0.f);
          acc[m][n][j] = v;
        }
    // row sums (each wave covers 64 of 256 cols; cross-wave via LDS atomics)
#pragma unroll
    for (int m = 0; m < 4; ++m)
#pragma unroll
      for (int j = 0; j < 4; ++j) {
        float s1 = acc[m][0][j] + acc[m][1][j] + acc[m][2][j] + acc[m][3][j];
        float s2 = acc[m][0][j] * acc[m][0][j] + acc[m][1][j] * acc[m][1][j] +
                   acc[m][2][j] * acc[m][2][j] + acc[m][3][j] * acc[m][3][j];
#pragma unroll
        for (int o = 1; o < 16; o <<= 1) {
          s1 += __shfl_xor(s1, o);
          s2 += __shfl_xor(s2, o);
        }
        if ((lane & 15) == 0) {
          int r = m * 16 + (lane >> 4) * 4 + j;
          atomicAdd(&sSum[r], s1);
          atomicAdd(&sSqs[r], s2);
        }
      }
    __syncthreads();
#pragma unroll
    for (int m = 0; m < 4; ++m)
#pragma unroll
      for (int j = 0; j < 4; ++j) {
        int r = m * 16 + (lane >> 4) * 4 + j;
        if (rowbase + r >= NNODES) continue;
        float mean = sSum[r] * (1.f / 256.f);
        float var = sSqs[r] * (1.f / 256.f) - mean * mean;
        float rstd = rsqrtf(var + 1e-5f);
#pragma unroll
        for (int n = 0; n < 4; ++n) {
          int c = wid * 64 + n * 16 + (lane & 15);
          float v = (acc[m][n][j] - mean) * rstd * gm[n] + bt[n];
          if (OUT_BF16)
            ((__bf16*)outp)[(rowbase + r) * FDIM + c] = f2b(v);
          else
            ((float*)outp)[(rowbase + r) * FDIM + c] = v;
        }
      }
  }
}

// ---------------- launch ----------------

extern "C" void kernel_launch(void* const* d_in, const int* in_sizes, int n_in,
                              void* d_out, int out_size, void* d_ws, size_t ws_size,
                              hipStream_t stream) {
  const int* xcat = (const int*)d_in[0];
  const int* edge = (const int*)d_in[1];
  const float* emb0 = (const float*)d_in[2];
  const float* emb1 = (const float*)d_in[3];
  const float* emb2 = (const float*)d_in[4];
  const float* emb3 = (const float*)d_in[5];
  const float* w1a = (const float*)d_in[6];
  const float* b1a = (const float*)d_in[7];
  const float* w1b = (const float*)d_in[8];
  const float* b1b = (const float*)d_in[9];
  const float* w2a = (const float*)d_in[10];
  const float* b2a = (const float*)d_in[11];
  const float* w2b = (const float*)d_in[12];
  const float* b2b = (const float*)d_in[13];
  const float* ln1g = (const float*)d_in[14];
  const float* ln1b = (const float*)d_in[15];
  const float* ln2g = (const float*)d_in[16];
  const float* ln2b = (const float*)d_in[17];
  float* outF = (float*)d_out;

  const int* srcP = edge;           // edge_index[0]
  const int* dstP = edge + NEDGES;  // edge_index[1]

  // workspace layout: bufA(bf16) | bufB(bf16) | col | rowptr | U
  // U = {cnt,cursor,partials} during CSR build, then overlaid by {wt, embt}.
  __bf16* bufA = (__bf16*)d_ws;                         // N*256 bf16 (agg out)
  __bf16* bufB = bufA + (size_t)NNODES * FDIM;          // N*256 bf16 (h1)
  int* col = (int*)(bufB + (size_t)NNODES * FDIM);      // E
  int* rowptr = col + NEDGES;                           // N+1 (padded to N+4)
  char* U = (char*)(rowptr + NNODES + 4);
  int* cnt = (int*)U;                                   // N
  int* cursor = cnt + NNODES;                           // N
  int* partials = cursor + NNODES;                      // 128
  __bf16* wt = (__bf16*)U;                              // 4 * 256 * 256 bf16
  __bf16* embt = wt + 262144;                           // 4 * 1000 * 64 bf16

  // ---- CSR build ----
  hipMemsetAsync(cnt, 0, (size_t)NNODES * sizeof(int), stream);
  k_count<<<2048, 256, 0, stream>>>(dstP, cnt);
  k_scan_part<<<NB_SCAN, 256, 0, stream>>>(cnt, partials);
  k_scan_partials<<<1, 128, 0, stream>>>(partials);
  k_scan_final<<<NB_SCAN, 256, 0, stream>>>(cnt, partials, rowptr, cursor);
  k_fill<<<2048, 256, 0, stream>>>(srcP, dstP, cursor, col);

  // ---- weight + embedding prep (cnt/cursor/partials dead now) ----
  k_prep_w<<<1024, 256, 0, stream>>>(w1a, w1b, w2a, w2b, wt);
  k_prep_emb<<<1000, 256, 0, stream>>>(emb0, emb1, emb2, emb3, embt);

  // ---- conv1: fused embed + aggregate -> bufA (bf16) ----
  k_agg_embed<<<NNODES / 4, 256, 0, stream>>>(xcat, embt, rowptr, col, bufA);
  // ---- conv1 MLP + relu + LN -> bufB (bf16 h1) ----
  k_mlp_mfma<1, 1><<<NBLK_MLP, 256, 0, stream>>>(bufA, bufB, wt, b1a, wt + 65536, b1b, ln1g, ln1b);
  // ---- conv2: aggregate h1 -> bufA (bf16) ----
  k_agg<<<NNODES / 4, 256, 0, stream>>>(bufB, rowptr, col, bufA);
  // ---- conv2 MLP + LN -> d_out (f32) ----
  k_mlp_mfma<0, 0><<<NBLK_MLP, 256, 0, stream>>>(bufA, outF, wt + 131072, b2a, wt + 196608, b2b, ln2g, ln2b);
}